// Round 1
// 156.294 us; speedup vs baseline: 1.0215x; 1.0215x over previous
//
#include <hip/hip_runtime.h>
#include <math.h>

#define L_DIM   8192
#define NCH     64
#define M_TOT_F 262144.0f
#define EPS_F   1e-5f

typedef float f32x4 __attribute__((ext_vector_type(4)));
typedef short bf16x8 __attribute__((ext_vector_type(8)));

union U8 { unsigned u[4]; bf16x8 v; };

// split two fp32 into packed bf16 hi (truncated) and bf16 lo (residual), 2 shorts per u32
__device__ __forceinline__ void cvt2(float f0, float f1, unsigned& h, unsigned& l) {
    unsigned u0 = __float_as_uint(f0), u1 = __float_as_uint(f1);
    h = (u0 >> 16) | (u1 & 0xFFFF0000u);
    float r0 = f0 - __uint_as_float(u0 & 0xFFFF0000u);
    float r1 = f1 - __uint_as_float(u1 & 0xFFFF0000u);
    l = (__float_as_uint(r0) >> 16) | (__float_as_uint(r1) & 0xFFFF0000u);
}

__device__ __forceinline__ void split16(float v, unsigned short& h, unsigned short& l) {
    unsigned u = __float_as_uint(v);
    h = (unsigned short)(u >> 16);
    float r = v - __uint_as_float(u & 0xFFFF0000u);
    l = (unsigned short)(__float_as_uint(r) >> 16);
}

__device__ __forceinline__ f32x4 mfma16(bf16x8 a, bf16x8 b, f32x4 c) {
    return __builtin_amdgcn_mfma_f32_16x16x32_bf16(a, b, c, 0, 0, 0);
}

__device__ __forceinline__ f32x4 fzero() {
    f32x4 z; z[0] = 0.f; z[1] = 0.f; z[2] = 0.f; z[3] = 0.f; return z;
}

// ---------------- K1: Gram partials (G1=hi*hi^T, G2=hi*lo^T) + row sums ----------------
// GTPB=4 / grid 1024: 4 blocks/CU (was 2). Double-buffered LDS planes -> 1 barrier/tile.
#define GTPB 4
__global__ __launch_bounds__(256) void gram_kernel(const float* __restrict__ X,
                                                   float* __restrict__ P) {
    __shared__ __align__(16) unsigned short hplane[2][64 * 72];
    __shared__ __align__(16) unsigned short lplane[2][64 * 72];
    const int tid  = threadIdx.x;
    const int w    = tid >> 6;
    const int lane = tid & 63;
    const int m    = lane & 15;
    const int q    = lane >> 4;
    const int lrow = tid >> 2;
    const int lq16 = (tid & 3) << 4;

    f32x4 acc1[4], acc2[4];
#pragma unroll
    for (int nb = 0; nb < 4; ++nb) { acc1[nb] = fzero(); acc2[nb] = fzero(); }
    float sacc = 0.f;

    const int tile0 = blockIdx.x * GTPB;
    float4 v[4];
    {
        int t = tile0;
        const float* src = X + ((size_t)((t >> 7) * NCH + lrow)) * L_DIM + ((t & 127) << 6) + lq16;
#pragma unroll
        for (int i = 0; i < 4; ++i) v[i] = ((const float4*)src)[i];
    }

    for (int t = 0; t < GTPB; ++t) {
        const int p = t & 1;
#pragma unroll
        for (int i = 0; i < 4; ++i) sacc += v[i].x + v[i].y + v[i].z + v[i].w;
        // cvt + write into buffer p (safe: readers of p from iter t-2 are separated
        // by the barrier of iter t-1; writers here are past that barrier)
#pragma unroll
        for (int i = 0; i < 4; ++i) {
            unsigned h0, l0, h1, l1;
            cvt2(v[i].x, v[i].y, h0, l0);
            cvt2(v[i].z, v[i].w, h1, l1);
            uint2 hh; hh.x = h0; hh.y = h1;
            uint2 ll; ll.x = l0; ll.y = l1;
            *(uint2*)&hplane[p][lrow * 72 + lq16 + 4 * i] = hh;
            *(uint2*)&lplane[p][lrow * 72 + lq16 + 4 * i] = ll;
        }
        if (t + 1 < GTPB) {
            int tn = tile0 + t + 1;
            const float* src = X + ((size_t)((tn >> 7) * NCH + lrow)) * L_DIM + ((tn & 127) << 6) + lq16;
#pragma unroll
            for (int i = 0; i < 4; ++i) v[i] = ((const float4*)src)[i];
        }
        __syncthreads();
#pragma unroll
        for (int k0 = 0; k0 < 64; k0 += 32) {
            bf16x8 a = *(const bf16x8*)&hplane[p][(16 * w + m) * 72 + k0 + 8 * q];
#pragma unroll
            for (int nb = 0; nb < 4; ++nb) {
                bf16x8 bh = *(const bf16x8*)&hplane[p][(16 * nb + m) * 72 + k0 + 8 * q];
                bf16x8 bl = *(const bf16x8*)&lplane[p][(16 * nb + m) * 72 + k0 + 8 * q];
                acc1[nb] = mfma16(a, bh, acc1[nb]);
                acc2[nb] = mfma16(a, bl, acc2[nb]);
            }
        }
    }

    float* base = P + (size_t)blockIdx.x * 8256;
#pragma unroll
    for (int nb = 0; nb < 4; ++nb)
#pragma unroll
        for (int r = 0; r < 4; ++r) {
            int grow = 16 * w + 4 * q + r;
            int gcol = 16 * nb + m;
            base[grow * 64 + gcol]        = acc1[nb][r];
            base[4096 + grow * 64 + gcol] = acc2[nb][r];
        }
    sacc += __shfl_xor(sacc, 1);
    sacc += __shfl_xor(sacc, 2);
    if ((tid & 3) == 0) base[8192 + lrow] = sacc;
}

// ---------------- K1b: reduce 1024 partials -> ws[0..8256) ----------------
__global__ __launch_bounds__(256) void reduce_kernel(const float* __restrict__ P,
                                                     float* __restrict__ ws) {
    const int tid = threadIdx.x;
    const int w = tid >> 6, lane = tid & 63;
    const int e0 = blockIdx.x * 64;
    float a = 0.f;
#pragma unroll 8
    for (int i = 0; i < 256; ++i)
        a += P[(size_t)(w * 256 + i) * 8256 + e0 + lane];
    __shared__ float red[4][64];
    red[w][lane] = a;
    __syncthreads();
    if (w == 0)
        ws[e0 + lane] = red[0][lane] + red[1][lane] + red[2][lane] + red[3][lane];
}

// ---------------- K2: Sigma -> Newton-Schulz (persistent bf16 hi/lo planes) -----------
// All matrices involved are symmetric (polynomials in Sigma_N), so D = A*B^T == A*B.
__device__ __forceinline__ void mm_core(f32x4* acc,
                                        const unsigned short* __restrict__ Xh,
                                        const unsigned short* __restrict__ Xl,
                                        const unsigned short* __restrict__ Yh,
                                        const unsigned short* __restrict__ Yl,
                                        int w, int m, int q) {
#pragma unroll
    for (int k0 = 0; k0 < 64; k0 += 32) {
        bf16x8 xh = *(const bf16x8*)&Xh[(16 * w + m) * 72 + k0 + 8 * q];
        bf16x8 xl = *(const bf16x8*)&Xl[(16 * w + m) * 72 + k0 + 8 * q];
#pragma unroll
        for (int nb = 0; nb < 4; ++nb) {
            bf16x8 yh = *(const bf16x8*)&Yh[(16 * nb + m) * 72 + k0 + 8 * q];
            bf16x8 yl = *(const bf16x8*)&Yl[(16 * nb + m) * 72 + k0 + 8 * q];
            acc[nb] = mfma16(xh, yh, acc[nb]);
            acc[nb] = mfma16(xh, yl, acc[nb]);
            acc[nb] = mfma16(xl, yh, acc[nb]);
        }
    }
}

__device__ __forceinline__ void mm_pl(unsigned short* __restrict__ Dh,
                                      unsigned short* __restrict__ Dl,
                                      const unsigned short* __restrict__ Xh,
                                      const unsigned short* __restrict__ Xl,
                                      const unsigned short* __restrict__ Yh,
                                      const unsigned short* __restrict__ Yl,
                                      int w, int m, int q) {
    f32x4 acc[4];
#pragma unroll
    for (int nb = 0; nb < 4; ++nb) acc[nb] = fzero();
    mm_core(acc, Xh, Xl, Yh, Yl, w, m, q);
#pragma unroll
    for (int nb = 0; nb < 4; ++nb)
#pragma unroll
        for (int r = 0; r < 4; ++r) {
            int row = 16 * w + 4 * q + r, col = 16 * nb + m;
            unsigned short h, l;
            split16(acc[nb][r], h, l);
            Dh[row * 72 + col] = h;
            Dl[row * 72 + col] = l;
        }
}

__global__ __launch_bounds__(256) void ns_kernel(float* __restrict__ ws) {
    __shared__ __align__(16) float Pf[64 * 68];
    __shared__ __align__(16) unsigned short Ph[64 * 72], Pl[64 * 72];
    __shared__ __align__(16) unsigned short Sh[64 * 72], Sl[64 * 72];
    __shared__ __align__(16) unsigned short T1h[64 * 72], T1l[64 * 72];
    __shared__ __align__(16) unsigned short T2h[64 * 72], T2l[64 * 72];
    __shared__ float mu[64];
    __shared__ float scal[2];

    const int tid = threadIdx.x;
    const int w = tid >> 6, lane = tid & 63;
    const int m = lane & 15, q = lane >> 4;
    const float inv_m = 1.0f / M_TOT_F;

    if (tid < 64) mu[tid] = ws[8192 + tid] * inv_m;
    __syncthreads();

    // Sigma (fp32) into Pf (temp)
    for (int e = tid; e < 4096; e += 256) {
        int i = e >> 6, j = e & 63;
        float g = (ws[e] + ws[4096 + e] + ws[4096 + (j << 6) + i]) * inv_m;
        Pf[i * 68 + j] = g - mu[i] * mu[j] + ((i == j) ? EPS_F : 0.f);
    }
    __syncthreads();

    if (tid < 64) {
        float v = Pf[tid * 68 + tid];
#pragma unroll
        for (int off = 32; off >= 1; off >>= 1) v += __shfl_xor(v, off);
        if (tid == 0) { scal[0] = 1.0f / v; scal[1] = sqrtf(1.0f / v); }
    }
    __syncthreads();
    const float rTr = scal[0];

    // S_N planes; closed-form first NS iteration: P1 = 1.5 I - 0.5 S_N
    for (int e = tid; e < 4096; e += 256) {
        int i = e >> 6, j = e & 63;
        float sn = Pf[i * 68 + j] * rTr;
        unsigned short h, l;
        split16(sn, h, l);
        Sh[i * 72 + j] = h; Sl[i * 72 + j] = l;
        float pv = ((i == j) ? 1.5f : 0.f) - 0.5f * sn;
        Pf[i * 68 + j] = pv;
        split16(pv, h, l);
        Ph[i * 72 + j] = h; Pl[i * 72 + j] = l;
    }
    __syncthreads();

    // remaining 4 NS iterations, bf16 planes converted once per production
    for (int it = 0; it < 4; ++it) {
        mm_pl(T1h, T1l, Ph, Pl, Ph, Pl, w, m, q);   // T1 = P^2
        __syncthreads();
        mm_pl(T2h, T2l, T1h, T1l, Ph, Pl, w, m, q); // T2 = P^3
        __syncthreads();
        f32x4 acc[4];                                // U = T2 * S_N
#pragma unroll
        for (int nb = 0; nb < 4; ++nb) acc[nb] = fzero();
        mm_core(acc, T2h, T2l, Sh, Sl, w, m, q);
#pragma unroll
        for (int nb = 0; nb < 4; ++nb)
#pragma unroll
            for (int r = 0; r < 4; ++r) {
                int row = 16 * w + 4 * q + r, col = 16 * nb + m;
                int idx = row * 68 + col;
                float pv = 1.5f * Pf[idx] - 0.5f * acc[nb][r];
                Pf[idx] = pv;
                unsigned short h, l;
                split16(pv, h, l);
                Ph[row * 72 + col] = h;
                Pl[row * 72 + col] = l;
            }
        __syncthreads();
    }

    const float s = scal[1];
    unsigned short* hp = (unsigned short*)ws;
    unsigned short* lp = hp + 4096;
    for (int e = tid; e < 4096; e += 256) {
        int i = e >> 6, j = e & 63;
        float v = Pf[i * 68 + j] * s;
        unsigned short h, l;
        split16(v, h, l);
        hp[e] = h;
        lp[e] = l;
    }
    if (tid < 64) {
        float a = 0.f;
#pragma unroll 8
        for (int k = 0; k < 64; ++k) a += Pf[tid * 68 + k] * mu[k];
        ws[8256 + tid] = -a * s;
    }
}

// ---------------- K3: Y = wm @ x + bias  (dbuf LDS planes -> 1 barrier/tile) ----------
#define ATPB 4
__global__ __launch_bounds__(256) void apply_kernel(const float* __restrict__ X,
                                                    float* __restrict__ Y,
                                                    const float* __restrict__ ws) {
    __shared__ __align__(16) unsigned short hplane[2][4096];
    __shared__ __align__(16) unsigned short lplane[2][4096];
    const int tid  = threadIdx.x;
    const int w    = tid >> 6;
    const int lane = tid & 63;
    const int m    = lane & 15;
    const int q    = lane >> 4;
    const int cp   = tid & 31;      // channel pair rows 2cp, 2cp+1
    const int lg   = tid >> 5;      // 0..7

    const unsigned short* hp = (const unsigned short*)ws;
    const unsigned short* lp = hp + 4096;
    bf16x8 Ah[2], Al[2];
#pragma unroll
    for (int kk = 0; kk < 2; ++kk) {
        Ah[kk] = *(const bf16x8*)&hp[(16 * w + m) * 64 + 32 * kk + 8 * q];
        Al[kk] = *(const bf16x8*)&lp[(16 * w + m) * 64 + 32 * kk + 8 * q];
    }
    const float4 bias4 = *(const float4*)&ws[8256 + 16 * w + 4 * q];

    float4 va[2], vb[2];   // rows 2cp / 2cp+1, two l-groups
    {
        int tile = blockIdx.x * ATPB;
        const float* xb = X + (size_t)(tile >> 7) * (NCH * L_DIM) + ((tile & 127) << 6)
                          + (size_t)(2 * cp) * L_DIM + 4 * lg;
#pragma unroll
        for (int s = 0; s < 2; ++s) {
            va[s] = *(const float4*)(xb + 32 * s);
            vb[s] = *(const float4*)(xb + 32 * s + L_DIM);
        }
    }

    for (int t = 0; t < ATPB; ++t) {
        int tile = blockIdx.x * ATPB + t;
        int bidx = tile >> 7;
        int l0   = (tile & 127) << 6;
        const int p = t & 1;
        unsigned* hw = (unsigned*)hplane[p];
        unsigned* lw = (unsigned*)lplane[p];

#pragma unroll
        for (int s = 0; s < 2; ++s) {
            float fa[4], fb[4];
            *(float4*)fa = va[s];
            *(float4*)fb = vb[s];
#pragma unroll
            for (int i = 0; i < 4; ++i) {
                int l = 4 * lg + 32 * s + i;
                unsigned h, lo2;
                cvt2(fa[i], fb[i], h, lo2);
                int widx = l * 32 + (((cp >> 2) ^ (l & 7)) << 2) + (cp & 3);
                hw[widx] = h;
                lw[widx] = lo2;
            }
        }

        if (t + 1 < ATPB) {
            int tn = tile + 1;
            const float* xb = X + (size_t)(tn >> 7) * (NCH * L_DIM) + ((tn & 127) << 6)
                              + (size_t)(2 * cp) * L_DIM + 4 * lg;
#pragma unroll
            for (int s = 0; s < 2; ++s) {
                va[s] = *(const float4*)(xb + 32 * s);
                vb[s] = *(const float4*)(xb + 32 * s + L_DIM);
            }
        }
        __syncthreads();

        f32x4 acc[4];
#pragma unroll
        for (int nb = 0; nb < 4; ++nb) {
            acc[nb][0] = bias4.x; acc[nb][1] = bias4.y;
            acc[nb][2] = bias4.z; acc[nb][3] = bias4.w;
        }
#pragma unroll
        for (int kk = 0; kk < 2; ++kk)
#pragma unroll
            for (int nb = 0; nb < 4; ++nb) {
                int l = 16 * nb + m;
                int saddr = l * 64 + ((((4 * kk + q) ^ (l & 7))) << 3);
                bf16x8 bh = *(const bf16x8*)&hplane[p][saddr];
                bf16x8 bl = *(const bf16x8*)&lplane[p][saddr];
                acc[nb] = mfma16(Ah[kk], bh, acc[nb]);
                acc[nb] = mfma16(Ah[kk], bl, acc[nb]);
                acc[nb] = mfma16(Al[kk], bh, acc[nb]);
            }

#pragma unroll
        for (int nb = 0; nb < 4; ++nb)
#pragma unroll
            for (int rr = 0; rr < 4; ++rr)
                Y[((size_t)bidx * NCH + 16 * w + 4 * q + rr) * L_DIM + l0 + 16 * nb + m] = acc[nb][rr];
    }
}

extern "C" void kernel_launch(void* const* d_in, const int* in_sizes, int n_in,
                              void* d_out, int out_size, void* d_ws, size_t ws_size,
                              hipStream_t stream) {
    const float* X = (const float*)d_in[0];
    float* Y  = (float*)d_out;
    float* ws = (float*)d_ws;
    float* scratch = (float*)d_out;   // gram partials live in d_out before apply overwrites it

    hipLaunchKernelGGL(gram_kernel,   dim3(1024), dim3(256), 0, stream, X, scratch);
    hipLaunchKernelGGL(reduce_kernel, dim3(129),  dim3(256), 0, stream, scratch, ws);
    hipLaunchKernelGGL(ns_kernel,     dim3(1),    dim3(256), 0, stream, ws);
    hipLaunchKernelGGL(apply_kernel,  dim3(1024), dim3(256), 0, stream, X, Y, ws);
}